// Round 2
// baseline (2940.469 us; speedup 1.0000x reference)
//
#include <hip/hip_runtime.h>

#define BM 128
#define BN 128
#define BK 32

constexpr int MM = 65536;   // batch
constexpr int KK = 512;     // inner dim
constexpr int NN = 512;     // out dim per layer

// C[M,N] = act(A[M,K] @ W[N,K]^T + bias[N])
// Thread (ty,tx) owns rows {ty+16i}, cols {tx+16j} -> fragment reads across a
// wave hit CONSECUTIVE LDS rows (stride 34 floats => banks 2*ty / 2*tx, all 32
// banks exactly once per b64 read: conflict-free). R0's ty*8+i mapping put all
// 16 rows on 2 bank-pairs (8-way conflict, 50% of kernel time).
template<bool RELU>
__global__ __launch_bounds__(256, 4) void gemm_bias_kernel(
    const float* __restrict__ A, const float* __restrict__ W,
    const float* __restrict__ bias, float* __restrict__ C) {
  __shared__ float As[BM][BK + 2];   // stride 34 floats, 8B-aligned for float2
  __shared__ float Bs[BN][BK + 2];
  const int tid = threadIdx.x;
  const int tx = tid & 15;   // 16 cols of threads
  const int ty = tid >> 4;   // 16 rows of threads
  const int bm = blockIdx.x;
  const int bn = blockIdx.y;
  const float* Ab = A + (size_t)bm * BM * KK;
  const float* Wb = W + (size_t)bn * BN * KK;

  float acc[8][8] = {};

  for (int k0 = 0; k0 < KK; k0 += BK) {
    // stage 128x32 A-tile and W-tile: 1024 float4 loads each, 4 per thread
#pragma unroll
    for (int t = 0; t < 4; ++t) {
      int s = tid + t * 256;
      int row = s >> 3;          // 0..127
      int kc = (s & 7) << 2;     // 0,4,..,28
      float4 va = *(const float4*)(Ab + (size_t)row * KK + k0 + kc);
      float4 vb = *(const float4*)(Wb + (size_t)row * KK + k0 + kc);
      *(float2*)&As[row][kc]     = make_float2(va.x, va.y);
      *(float2*)&As[row][kc + 2] = make_float2(va.z, va.w);
      *(float2*)&Bs[row][kc]     = make_float2(vb.x, vb.y);
      *(float2*)&Bs[row][kc + 2] = make_float2(vb.z, vb.w);
    }
    __syncthreads();
#pragma unroll 8
    for (int kk = 0; kk < BK; kk += 2) {
      float2 a[8], b[8];
#pragma unroll
      for (int i = 0; i < 8; ++i) a[i] = *(const float2*)&As[ty + 16 * i][kk];
#pragma unroll
      for (int j = 0; j < 8; ++j) b[j] = *(const float2*)&Bs[tx + 16 * j][kk];
#pragma unroll
      for (int i = 0; i < 8; ++i)
#pragma unroll
        for (int j = 0; j < 8; ++j)
          acc[i][j] += a[i].x * b[j].x + a[i].y * b[j].y;
    }
    __syncthreads();
  }

  // Epilogue: strided scalar stores (rows ty+16i, cols tx+16j). Each wave
  // instruction writes 4 rows x 16 consecutive floats (64B segments) — the 8
  // j-instructions together cover full 512B rows, L2 merges the lines.
  const int col_base = bn * BN + tx;
  float bv[8];
#pragma unroll
  for (int j = 0; j < 8; ++j) bv[j] = bias[col_base + 16 * j];
#pragma unroll
  for (int i = 0; i < 8; ++i) {
    size_t row = (size_t)bm * BM + ty + 16 * i;
    float* Crow = C + row * NN + col_base;
#pragma unroll
    for (int j = 0; j < 8; ++j) {
      float v = acc[i][j] + bv[j];
      if (RELU) v = fmaxf(v, 0.f);
      Crow[16 * j] = v;
    }
  }
}

// Per 16 batch rows: logits = m @ Wc^T + bc ; y = argmax(logits) (softmax is
// monotonic, probs unused) ; z[e] = m . Wg[y, e, :] + bg[y, e] for e<16.
__global__ __launch_bounds__(256) void head_kernel(
    const float* __restrict__ m2, const float* __restrict__ Wc,
    const float* __restrict__ bc, const float* __restrict__ Wg,
    const float* __restrict__ bg, float* __restrict__ z_out,
    float* __restrict__ y_out) {
  __shared__ float sm[16][516];   // stride 516: float4-aligned
  __shared__ float sw[16][516];
  __shared__ float slog[16][17];
  __shared__ int sy[16];
  const int tid = threadIdx.x;
  const int r = tid >> 4;    // row within block
  const int c = tid & 15;    // class / latent index
  const size_t row0 = (size_t)blockIdx.x * 16;

  // stage 16 m-rows (32 KB) and full Wc (32 KB): 2048 float4 each, 8/thread
#pragma unroll
  for (int t = 0; t < 8; ++t) {
    int s = tid + t * 256;         // 0..2047
    int rr = s >> 7;               // 0..15
    int kc = (s & 127) << 2;       // 0..508
    *(float4*)&sm[rr][kc] = *(const float4*)(m2 + (row0 + rr) * 512 + kc);
    *(float4*)&sw[rr][kc] = *(const float4*)(Wc + (size_t)rr * 512 + kc);
  }
  __syncthreads();

  float dot = 0.f;
#pragma unroll 8
  for (int k = 0; k < 512; k += 4) {
    float4 a = *(const float4*)&sm[r][k];
    float4 w = *(const float4*)&sw[c][k];
    dot += a.x * w.x + a.y * w.y + a.z * w.z + a.w * w.w;
  }
  slog[r][c] = dot + bc[c];
  __syncthreads();

  if (c == 0) {
    // strict > keeps first max: matches np/jnp argmax tie-breaking
    float best = slog[r][0];
    int bi = 0;
#pragma unroll
    for (int j = 1; j < 16; ++j) {
      float v = slog[r][j];
      if (v > best) { best = v; bi = j; }
    }
    sy[r] = bi;
    y_out[row0 + r] = (float)bi;
  }
  __syncthreads();

  const int y = sy[r];
  const float* wg = Wg + ((size_t)y * 32 + c) * 512;  // Wg[y, c, :], c < 16 = mu part
  float zacc = 0.f;
#pragma unroll 8
  for (int k = 0; k < 512; k += 4) {
    float4 a = *(const float4*)&sm[r][k];
    float4 w = *(const float4*)(wg + k);
    zacc += a.x * w.x + a.y * w.y + a.z * w.z + a.w * w.w;
  }
  z_out[(row0 + r) * 16 + c] = zacc + bg[y * 32 + c];
}

extern "C" void kernel_launch(void* const* d_in, const int* in_sizes, int n_in,
                              void* d_out, int out_size, void* d_ws, size_t ws_size,
                              hipStream_t stream) {
  const float* x  = (const float*)d_in[0];
  const float* W0 = (const float*)d_in[1];
  const float* b0 = (const float*)d_in[2];
  const float* W1 = (const float*)d_in[3];
  const float* b1 = (const float*)d_in[4];
  const float* W2 = (const float*)d_in[5];
  const float* b2 = (const float*)d_in[6];
  const float* Wc = (const float*)d_in[7];
  const float* bc = (const float*)d_in[8];
  const float* Wg = (const float*)d_in[9];
  const float* bg = (const float*)d_in[10];

  float* m0 = (float*)d_ws;                       // 65536*512 floats = 128 MB
  float* m1 = m0 + (size_t)MM * KK;               // second 128 MB
  float* z_out = (float*)d_out;                   // 65536*16 floats
  float* y_out = z_out + (size_t)MM * 16;         // 65536 floats (argmax as float)

  dim3 grid(MM / BM, NN / BN);
  gemm_bias_kernel<true ><<<grid, 256, 0, stream>>>(x,  W0, b0, m0);
  gemm_bias_kernel<true ><<<grid, 256, 0, stream>>>(m0, W1, b1, m1);
  gemm_bias_kernel<false><<<grid, 256, 0, stream>>>(m1, W2, b2, m0);
  head_kernel<<<MM / 16, 256, 0, stream>>>(m0, Wc, bc, Wg, bg, z_out, y_out);
}

// Round 3
// 2114.398 us; speedup vs baseline: 1.3907x; 1.3907x over previous
//
#include <hip/hip_runtime.h>

#define BM 128
#define BN 128
#define BK 32

constexpr int MM = 65536;   // batch
constexpr int KK = 512;     // inner dim
constexpr int NN = 512;     // out dim per layer

// C[M,N] = act(A[M,K] @ W[N,K]^T + bias[N])
// Thread (ty,tx) owns rows {ty+16i}, cols {tx+16j} -> fragment reads across a
// wave hit CONSECUTIVE LDS rows (stride 34 floats => banks 2*ty / 2*tx, all 32
// banks exactly once per b64 read: conflict-free, verified R1: conflicts 2.8e8 -> 0).
// launch_bounds(256,2): R1's (256,4) squeezed the unified reg file to 64 VGPR
// + AGPR shuffle/spills (+1 GB HBM scratch traffic per dispatch). LDS caps
// occupancy at 4 blocks/CU anyway; give the allocator 256 regs.
template<bool RELU>
__global__ __launch_bounds__(256, 2) void gemm_bias_kernel(
    const float* __restrict__ A, const float* __restrict__ W,
    const float* __restrict__ bias, float* __restrict__ C) {
  __shared__ float As[BM][BK + 2];   // stride 34 floats, 8B-aligned for float2
  __shared__ float Bs[BN][BK + 2];
  const int tid = threadIdx.x;
  const int tx = tid & 15;   // 16 cols of threads
  const int ty = tid >> 4;   // 16 rows of threads
  const int bm = blockIdx.x;
  const int bn = blockIdx.y;
  const float* Ab = A + (size_t)bm * BM * KK;
  const float* Wb = W + (size_t)bn * BN * KK;

  float acc[8][8] = {};

  for (int k0 = 0; k0 < KK; k0 += BK) {
    // stage 128x32 A-tile and W-tile: 1024 float4 loads each, 4 per thread
#pragma unroll
    for (int t = 0; t < 4; ++t) {
      int s = tid + t * 256;
      int row = s >> 3;          // 0..127
      int kc = (s & 7) << 2;     // 0,4,..,28
      float4 va = *(const float4*)(Ab + (size_t)row * KK + k0 + kc);
      float4 vb = *(const float4*)(Wb + (size_t)row * KK + k0 + kc);
      *(float2*)&As[row][kc]     = make_float2(va.x, va.y);
      *(float2*)&As[row][kc + 2] = make_float2(va.z, va.w);
      *(float2*)&Bs[row][kc]     = make_float2(vb.x, vb.y);
      *(float2*)&Bs[row][kc + 2] = make_float2(vb.z, vb.w);
    }
    __syncthreads();
#pragma unroll 8
    for (int kk = 0; kk < BK; kk += 2) {
      float2 a[8], b[8];
#pragma unroll
      for (int i = 0; i < 8; ++i) a[i] = *(const float2*)&As[ty + 16 * i][kk];
#pragma unroll
      for (int j = 0; j < 8; ++j) b[j] = *(const float2*)&Bs[tx + 16 * j][kk];
#pragma unroll
      for (int i = 0; i < 8; ++i)
#pragma unroll
        for (int j = 0; j < 8; ++j)
          acc[i][j] += a[i].x * b[j].x + a[i].y * b[j].y;
    }
    __syncthreads();
  }

  // Epilogue: strided stores (rows ty+16i, cols tx+16j). Each wave instruction
  // writes 4 rows x 64B contiguous segments; the 8 j-instructions cover full
  // 512B rows, merged in L2. (R1 WRITE_SIZE blowup was spills, not this: watch
  // WRITE_SIZE ~= 131 MB to confirm.)
  const int col_base = bn * BN + tx;
  float bv[8];
#pragma unroll
  for (int j = 0; j < 8; ++j) bv[j] = bias[col_base + 16 * j];
#pragma unroll
  for (int i = 0; i < 8; ++i) {
    size_t row = (size_t)bm * BM + ty + 16 * i;
    float* Crow = C + row * NN + col_base;
#pragma unroll
    for (int j = 0; j < 8; ++j) {
      float v = acc[i][j] + bv[j];
      if (RELU) v = fmaxf(v, 0.f);
      Crow[16 * j] = v;
    }
  }
}

// Per 16 batch rows: logits = m @ Wc^T + bc ; y = argmax(logits) (softmax is
// monotonic, probs unused) ; z[e] = m . Wg[y, e, :] + bg[y, e] for e<16.
__global__ __launch_bounds__(256) void head_kernel(
    const float* __restrict__ m2, const float* __restrict__ Wc,
    const float* __restrict__ bc, const float* __restrict__ Wg,
    const float* __restrict__ bg, float* __restrict__ z_out,
    float* __restrict__ y_out) {
  __shared__ float sm[16][516];   // stride 516: float4-aligned
  __shared__ float sw[16][516];
  __shared__ float slog[16][17];
  __shared__ int sy[16];
  const int tid = threadIdx.x;
  const int r = tid >> 4;    // row within block
  const int c = tid & 15;    // class / latent index
  const size_t row0 = (size_t)blockIdx.x * 16;

  // stage 16 m-rows (32 KB) and full Wc (32 KB): 2048 float4 each, 8/thread
#pragma unroll
  for (int t = 0; t < 8; ++t) {
    int s = tid + t * 256;         // 0..2047
    int rr = s >> 7;               // 0..15
    int kc = (s & 127) << 2;       // 0..508
    *(float4*)&sm[rr][kc] = *(const float4*)(m2 + (row0 + rr) * 512 + kc);
    *(float4*)&sw[rr][kc] = *(const float4*)(Wc + (size_t)rr * 512 + kc);
  }
  __syncthreads();

  float dot = 0.f;
#pragma unroll 8
  for (int k = 0; k < 512; k += 4) {
    float4 a = *(const float4*)&sm[r][k];
    float4 w = *(const float4*)&sw[c][k];
    dot += a.x * w.x + a.y * w.y + a.z * w.z + a.w * w.w;
  }
  slog[r][c] = dot + bc[c];
  __syncthreads();

  if (c == 0) {
    // strict > keeps first max: matches np/jnp argmax tie-breaking
    float best = slog[r][0];
    int bi = 0;
#pragma unroll
    for (int j = 1; j < 16; ++j) {
      float v = slog[r][j];
      if (v > best) { best = v; bi = j; }
    }
    sy[r] = bi;
    y_out[row0 + r] = (float)bi;
  }
  __syncthreads();

  const int y = sy[r];
  const float* wg = Wg + ((size_t)y * 32 + c) * 512;  // Wg[y, c, :], c < 16 = mu part
  float zacc = 0.f;
#pragma unroll 8
  for (int k = 0; k < 512; k += 4) {
    float4 a = *(const float4*)&sm[r][k];
    float4 w = *(const float4*)(wg + k);
    zacc += a.x * w.x + a.y * w.y + a.z * w.z + a.w * w.w;
  }
  z_out[(row0 + r) * 16 + c] = zacc + bg[y * 32 + c];
}

extern "C" void kernel_launch(void* const* d_in, const int* in_sizes, int n_in,
                              void* d_out, int out_size, void* d_ws, size_t ws_size,
                              hipStream_t stream) {
  const float* x  = (const float*)d_in[0];
  const float* W0 = (const float*)d_in[1];
  const float* b0 = (const float*)d_in[2];
  const float* W1 = (const float*)d_in[3];
  const float* b1 = (const float*)d_in[4];
  const float* W2 = (const float*)d_in[5];
  const float* b2 = (const float*)d_in[6];
  const float* Wc = (const float*)d_in[7];
  const float* bc = (const float*)d_in[8];
  const float* Wg = (const float*)d_in[9];
  const float* bg = (const float*)d_in[10];

  float* m0 = (float*)d_ws;                       // 65536*512 floats = 128 MB
  float* m1 = m0 + (size_t)MM * KK;               // second 128 MB
  float* z_out = (float*)d_out;                   // 65536*16 floats
  float* y_out = z_out + (size_t)MM * 16;         // 65536 floats (argmax as float)

  dim3 grid(MM / BM, NN / BN);
  gemm_bias_kernel<true ><<<grid, 256, 0, stream>>>(x,  W0, b0, m0);
  gemm_bias_kernel<true ><<<grid, 256, 0, stream>>>(m0, W1, b1, m1);
  gemm_bias_kernel<false><<<grid, 256, 0, stream>>>(m1, W2, b2, m0);
  head_kernel<<<MM / 16, 256, 0, stream>>>(m0, Wc, bc, Wg, bg, z_out, y_out);
}

// Round 4
// 897.653 us; speedup vs baseline: 3.2757x; 2.3555x over previous
//
#include <hip/hip_runtime.h>
#include <hip/hip_bf16.h>

typedef __attribute__((ext_vector_type(8))) short short8;
typedef __attribute__((ext_vector_type(16))) float floatx16;

constexpr int MM = 65536;   // batch
constexpr int KK = 512;     // inner dim
constexpr int NN = 512;     // out dim per layer

#define GM 128
#define GN 128
#define GK 32
#define LDT 40   // LDS row stride in bf16: row base bank = 20*r mod 32 -> good rotation

// round-to-nearest-even fp32 -> bf16 (bit-level, finite inputs)
__device__ __forceinline__ unsigned short bf16_rn(float v) {
  unsigned u = __float_as_uint(v);
  return (unsigned short)((u + 0x7FFFu + ((u >> 16) & 1u)) >> 16);
}
__device__ __forceinline__ float bf16_to_f32(unsigned short h) {
  return __uint_as_float((unsigned)h << 16);
}

// src fp32 -> (hi, lo) bf16 arrays. n4 = element count / 4.
__global__ __launch_bounds__(256) void split_kernel(
    const float* __restrict__ src, unsigned short* __restrict__ h,
    unsigned short* __restrict__ l, int n4) {
  int i = blockIdx.x * 256 + threadIdx.x;
  if (i >= n4) return;
  float4 v = ((const float4*)src)[i];
  ushort4 hv, lv;
  hv.x = bf16_rn(v.x); lv.x = bf16_rn(v.x - bf16_to_f32(hv.x));
  hv.y = bf16_rn(v.y); lv.y = bf16_rn(v.y - bf16_to_f32(hv.y));
  hv.z = bf16_rn(v.z); lv.z = bf16_rn(v.z - bf16_to_f32(hv.z));
  hv.w = bf16_rn(v.w); lv.w = bf16_rn(v.w - bf16_to_f32(hv.w));
  ((ushort4*)h)[i] = hv;
  ((ushort4*)l)[i] = lv;
}

// C[M,N] = act(A @ W^T + bias) via 3-term split-bf16 MFMA:
// A ~ Ah+Al, W ~ Wh+Wl (bf16); C ~ Ah*Wh + Ah*Wl + Al*Wh (Al*Wl ~ 2^-18, dropped).
// v_mfma_f32_32x32x16_bf16: A/B frag = 8 consecutive k per lane
// (row = lane&31, k = (lane>>5)*8 + j, verified layout family m74/m90/m97);
// C/D: col = lane&31, row = (reg&3) + 8*(reg>>2) + 4*(lane>>5)  [m74/m101].
// 4 waves, each computes a 64x64 quadrant (2x2 tiles of 32x32).
template<bool RELU, bool SPLIT>
__global__ __launch_bounds__(256, 2) void gemm_mfma(
    const unsigned short* __restrict__ Ah, const unsigned short* __restrict__ Al,
    const unsigned short* __restrict__ Wh, const unsigned short* __restrict__ Wl,
    const float* __restrict__ bias,
    unsigned short* __restrict__ Ch, unsigned short* __restrict__ Cl,
    float* __restrict__ Cf) {
  __shared__ unsigned short sAh[GM][LDT], sAl[GM][LDT];
  __shared__ unsigned short sBh[GN][LDT], sBl[GN][LDT];
  const int tid = threadIdx.x;
  const int lane = tid & 63;
  const int wid = tid >> 6;
  const int wr = wid >> 1;         // wave row (0..1)
  const int wc = wid & 1;          // wave col (0..1)
  const int bm = blockIdx.x, bn = blockIdx.y;
  const size_t Abase = (size_t)bm * GM * KK;
  const size_t Bbase = (size_t)bn * GN * KK;

  floatx16 acc[2][2];
#pragma unroll
  for (int i = 0; i < 2; ++i)
#pragma unroll
    for (int j = 0; j < 2; ++j)
#pragma unroll
      for (int r = 0; r < 16; ++r) acc[i][j][r] = 0.f;

  for (int k0 = 0; k0 < KK; k0 += GK) {
    // stage 128x32 bf16 tiles for all 4 arrays: 2 b128 loads per array per thread
#pragma unroll
    for (int t = 0; t < 2; ++t) {
      int s = tid + t * 256;
      int row = s >> 2;            // 0..127
      int cc = (s & 3) * 8;        // 0,8,16,24
      size_t goff = (size_t)row * KK + k0 + cc;
      *(short8*)&sAh[row][cc] = *(const short8*)(Ah + Abase + goff);
      *(short8*)&sAl[row][cc] = *(const short8*)(Al + Abase + goff);
      *(short8*)&sBh[row][cc] = *(const short8*)(Wh + Bbase + goff);
      *(short8*)&sBl[row][cc] = *(const short8*)(Wl + Bbase + goff);
    }
    __syncthreads();

#pragma unroll
    for (int ks = 0; ks < 2; ++ks) {
      const int ko = ks * 16 + (lane >> 5) * 8;
      short8 fah[2], fal[2], fbh[2], fbl[2];
#pragma unroll
      for (int ri = 0; ri < 2; ++ri) {
        int row = wr * 64 + ri * 32 + (lane & 31);
        fah[ri] = *(const short8*)&sAh[row][ko];
        fal[ri] = *(const short8*)&sAl[row][ko];
      }
#pragma unroll
      for (int si = 0; si < 2; ++si) {
        int col = wc * 64 + si * 32 + (lane & 31);
        fbh[si] = *(const short8*)&sBh[col][ko];
        fbl[si] = *(const short8*)&sBl[col][ko];
      }
#pragma unroll
      for (int ri = 0; ri < 2; ++ri)
#pragma unroll
        for (int si = 0; si < 2; ++si) {
          acc[ri][si] = __builtin_amdgcn_mfma_f32_32x32x16_bf16(fah[ri], fbh[si], acc[ri][si], 0, 0, 0);
          acc[ri][si] = __builtin_amdgcn_mfma_f32_32x32x16_bf16(fah[ri], fbl[si], acc[ri][si], 0, 0, 0);
          acc[ri][si] = __builtin_amdgcn_mfma_f32_32x32x16_bf16(fal[ri], fbh[si], acc[ri][si], 0, 0, 0);
        }
    }
    __syncthreads();
  }

  // epilogue: bias + optional relu; write bf16 split pair or fp32
#pragma unroll
  for (int si = 0; si < 2; ++si) {
    int col = bn * GN + wc * 64 + si * 32 + (lane & 31);
    float bv = bias[col];
#pragma unroll
    for (int ri = 0; ri < 2; ++ri) {
#pragma unroll
      for (int r = 0; r < 16; ++r) {
        int row = bm * GM + wr * 64 + ri * 32 + (r & 3) + 8 * (r >> 2) + 4 * (lane >> 5);
        float v = acc[ri][si][r] + bv;
        if (RELU) v = fmaxf(v, 0.f);
        size_t idx = (size_t)row * NN + col;
        if (SPLIT) {
          unsigned short h = bf16_rn(v);
          Ch[idx] = h;
          Cl[idx] = bf16_rn(v - bf16_to_f32(h));
        } else {
          Cf[idx] = v;
        }
      }
    }
  }
}

// Per 16 batch rows: logits = m @ Wc^T + bc ; y = argmax(logits) (softmax is
// monotonic, probs unused) ; z[e] = m . Wg[y, e, :] + bg[y, e] for e<16.
__global__ __launch_bounds__(256) void head_kernel(
    const float* __restrict__ m2, const float* __restrict__ Wc,
    const float* __restrict__ bc, const float* __restrict__ Wg,
    const float* __restrict__ bg, float* __restrict__ z_out,
    float* __restrict__ y_out) {
  __shared__ float sm[16][516];
  __shared__ float sw[16][516];
  __shared__ float slog[16][17];
  __shared__ int sy[16];
  const int tid = threadIdx.x;
  const int r = tid >> 4;
  const int c = tid & 15;
  const size_t row0 = (size_t)blockIdx.x * 16;

#pragma unroll
  for (int t = 0; t < 8; ++t) {
    int s = tid + t * 256;
    int rr = s >> 7;
    int kc = (s & 127) << 2;
    *(float4*)&sm[rr][kc] = *(const float4*)(m2 + (row0 + rr) * 512 + kc);
    *(float4*)&sw[rr][kc] = *(const float4*)(Wc + (size_t)rr * 512 + kc);
  }
  __syncthreads();

  float dot = 0.f;
#pragma unroll 8
  for (int k = 0; k < 512; k += 4) {
    float4 a = *(const float4*)&sm[r][k];
    float4 w = *(const float4*)&sw[c][k];
    dot += a.x * w.x + a.y * w.y + a.z * w.z + a.w * w.w;
  }
  slog[r][c] = dot + bc[c];
  __syncthreads();

  if (c == 0) {
    float best = slog[r][0];
    int bi = 0;
#pragma unroll
    for (int j = 1; j < 16; ++j) {
      float v = slog[r][j];
      if (v > best) { best = v; bi = j; }
    }
    sy[r] = bi;
    y_out[row0 + r] = (float)bi;
  }
  __syncthreads();

  const int y = sy[r];
  const float* wg = Wg + ((size_t)y * 32 + c) * 512;
  float zacc = 0.f;
#pragma unroll 8
  for (int k = 0; k < 512; k += 4) {
    float4 a = *(const float4*)&sm[r][k];
    float4 w = *(const float4*)(wg + k);
    zacc += a.x * w.x + a.y * w.y + a.z * w.z + a.w * w.w;
  }
  z_out[(row0 + r) * 16 + c] = zacc + bg[y * 32 + c];
}

extern "C" void kernel_launch(void* const* d_in, const int* in_sizes, int n_in,
                              void* d_out, int out_size, void* d_ws, size_t ws_size,
                              hipStream_t stream) {
  const float* x  = (const float*)d_in[0];
  const float* W0 = (const float*)d_in[1];
  const float* b0 = (const float*)d_in[2];
  const float* W1 = (const float*)d_in[3];
  const float* b1 = (const float*)d_in[4];
  const float* W2 = (const float*)d_in[5];
  const float* b2 = (const float*)d_in[6];
  const float* Wc = (const float*)d_in[7];
  const float* bc = (const float*)d_in[8];
  const float* Wg = (const float*)d_in[9];
  const float* bg = (const float*)d_in[10];

  const size_t NEL = (size_t)MM * KK;         // 33.5M elements
  // ws: two 128 MiB pair-buffers (same 256 MiB footprint as fp32 ping-pong)
  unsigned short* Ah = (unsigned short*)d_ws;           // 64 MiB
  unsigned short* Al = Ah + NEL;                        // 64 MiB
  unsigned short* Bh = Al + NEL;                        // 64 MiB
  unsigned short* Bl = Bh + NEL;                        // 64 MiB
  float* m3 = (float*)Bh;                               // GEMM3 out reuses bufB as fp32 (128 MiB)

  // W splits staged in d_out (3 MiB < 4.25 MiB); head fully overwrites d_out last.
  unsigned short* w0h = (unsigned short*)d_out;
  unsigned short* w0l = w0h + 262144;
  unsigned short* w1h = w0l + 262144;
  unsigned short* w1l = w1h + 262144;
  unsigned short* w2h = w1l + 262144;
  unsigned short* w2l = w2h + 262144;

  float* z_out = (float*)d_out;
  float* y_out = z_out + (size_t)MM * 16;

  // splits
  split_kernel<<<(int)(NEL / 4 / 256), 256, 0, stream>>>(x, Ah, Al, (int)(NEL / 4));
  split_kernel<<<256, 256, 0, stream>>>(W0, w0h, w0l, 65536);
  split_kernel<<<256, 256, 0, stream>>>(W1, w1h, w1l, 65536);
  split_kernel<<<256, 256, 0, stream>>>(W2, w2h, w2l, 65536);

  dim3 grid(MM / GM, NN / GN);
  // L1: x-pair -> bufB pair (relu, split out)
  gemm_mfma<true , true ><<<grid, 256, 0, stream>>>(Ah, Al, w0h, w0l, b0, Bh, Bl, nullptr);
  // L2: bufB pair -> bufA pair (relu, split out)
  gemm_mfma<true , true ><<<grid, 256, 0, stream>>>(Bh, Bl, w1h, w1l, b1, Ah, Al, nullptr);
  // L3: bufA pair -> m3 fp32 (no relu)
  gemm_mfma<false, false><<<grid, 256, 0, stream>>>(Ah, Al, w2h, w2l, b2, nullptr, nullptr, m3);
  // head
  head_kernel<<<MM / 16, 256, 0, stream>>>(m3, Wc, bc, Wg, bg, z_out, y_out);
}